// Round 6
// baseline (104.740 us; speedup 1.0000x reference)
//
#include <hip/hip_runtime.h>

// Problem constants (fixed by the reference: N=8192, F=256).
#define NN 8192
#define FF 256

typedef float floatx4 __attribute__((ext_vector_type(4)));

// Kernel 1: per-row dual dot product.
// One 64-lane wave per row; F=256 = 64 lanes x float4.
__global__ void row_scores_kernel(const float* __restrict__ x,
                                  const float* __restrict__ W,
                                  const float* __restrict__ b,
                                  float* __restrict__ left,
                                  float* __restrict__ right) {
    const int row  = (int)((blockIdx.x * blockDim.x + threadIdx.x) >> 6);
    const int lane = (int)(threadIdx.x & 63);
    if (row >= NN) return;

    const floatx4 xv = reinterpret_cast<const floatx4*>(x + (size_t)row * FF)[lane];
    const floatx4 wl = reinterpret_cast<const floatx4*>(W)[lane];
    const floatx4 wr = reinterpret_cast<const floatx4*>(W + FF)[lane];

    float l = xv.x * wl.x + xv.y * wl.y + xv.z * wl.z + xv.w * wl.w;
    float r = xv.x * wr.x + xv.y * wr.y + xv.z * wr.z + xv.w * wr.w;

    #pragma unroll
    for (int off = 32; off; off >>= 1) {
        l += __shfl_down(l, off, 64);
        r += __shfl_down(r, off, 64);
    }
    if (lane == 0) {
        left[row]  = l + b[0];
        right[row] = r;
    }
}

__device__ __forceinline__ float sigmoid_fast(float s) {
    return __builtin_amdgcn_rcpf(1.0f + __expf(-s));
}

// Kernel 2: out[i,j] = adj[i,j] * sigmoid(left[i] + right[j])
// Block b owns rows [4b, 4b+4). rq[8] (right quads) hoisted once per block.
// 2-deep software pipeline across rows: prefetch row k+1's 8 adj quads into
// the alternate register buffer BEFORE computing row k, so ~8 loads stay in
// flight through the compute+store phase. __launch_bounds__(256,4) raises the
// VGPR cap (~128) so the compiler can actually keep both buffers + rq live
// (R5's 48-VGPR allocation couldn't hold 8 in-flight loads at all).
#define ROWS_PER_BLOCK 4
#define Q_PER_ROW (NN / 4 / 256)   // 8 float4-quads per thread per row

__global__ __launch_bounds__(256, 4) void att_kernel(const float* __restrict__ adj,
                                                     const float* __restrict__ left,
                                                     const float* __restrict__ right,
                                                     float* __restrict__ out) {
    const unsigned t  = threadIdx.x;
    const unsigned r0 = blockIdx.x * ROWS_PER_BLOCK;

    const floatx4* __restrict__ adj4   = reinterpret_cast<const floatx4*>(adj);
    const floatx4* __restrict__ right4 = reinterpret_cast<const floatx4*>(right);
    floatx4* __restrict__ out4         = reinterpret_cast<floatx4*>(out);

    // Hoist this thread's right-quads (reused by all 4 rows).
    floatx4 rq[Q_PER_ROW];
    #pragma unroll
    for (int q = 0; q < Q_PER_ROW; ++q)
        rq[q] = right4[t + (unsigned)q * 256u];

    const unsigned base = r0 * (NN / 4) + t;

    // Prologue: prefetch row 0 into A.
    floatx4 A[Q_PER_ROW], B[Q_PER_ROW];
    #pragma unroll
    for (int q = 0; q < Q_PER_ROW; ++q)
        A[q] = adj4[base + (unsigned)q * 256u];

    #pragma unroll 1
    for (int kk = 0; kk < ROWS_PER_BLOCK; kk += 2) {
        // Prefetch row kk+1 into B (independent of A-compute below).
        #pragma unroll
        for (int q = 0; q < Q_PER_ROW; ++q)
            B[q] = adj4[base + (unsigned)(kk + 1) * (NN / 4) + (unsigned)q * 256u];

        // Compute + store row kk from A.
        {
            const float li = left[r0 + kk];   // uniform scalar load, no array idx
            #pragma unroll
            for (int q = 0; q < Q_PER_ROW; ++q) {
                const unsigned idx = base + (unsigned)kk * (NN / 4) + (unsigned)q * 256u;
                floatx4 o;
                o.x = A[q].x * sigmoid_fast(li + rq[q].x);
                o.y = A[q].y * sigmoid_fast(li + rq[q].y);
                o.z = A[q].z * sigmoid_fast(li + rq[q].z);
                o.w = A[q].w * sigmoid_fast(li + rq[q].w);
                __builtin_nontemporal_store(o, &out4[idx]);
            }
        }

        // Prefetch row kk+2 into A (skipped on last pair; uniform branch).
        if (kk + 2 < ROWS_PER_BLOCK) {
            #pragma unroll
            for (int q = 0; q < Q_PER_ROW; ++q)
                A[q] = adj4[base + (unsigned)(kk + 2) * (NN / 4) + (unsigned)q * 256u];
        }

        // Compute + store row kk+1 from B.
        {
            const float li = left[r0 + kk + 1];
            #pragma unroll
            for (int q = 0; q < Q_PER_ROW; ++q) {
                const unsigned idx = base + (unsigned)(kk + 1) * (NN / 4) + (unsigned)q * 256u;
                floatx4 o;
                o.x = B[q].x * sigmoid_fast(li + rq[q].x);
                o.y = B[q].y * sigmoid_fast(li + rq[q].y);
                o.z = B[q].z * sigmoid_fast(li + rq[q].z);
                o.w = B[q].w * sigmoid_fast(li + rq[q].w);
                __builtin_nontemporal_store(o, &out4[idx]);
            }
        }
    }
}

extern "C" void kernel_launch(void* const* d_in, const int* in_sizes, int n_in,
                              void* d_out, int out_size, void* d_ws, size_t ws_size,
                              hipStream_t stream) {
    const float* x   = (const float*)d_in[0];   // [N, F]
    const float* adj = (const float*)d_in[1];   // [N, N]
    const float* W   = (const float*)d_in[2];   // [2F, 1]
    const float* b   = (const float*)d_in[3];   // [1]
    float* out = (float*)d_out;                 // [N, N]

    float* left  = (float*)d_ws;                // N floats
    float* right = left + NN;                   // N floats

    row_scores_kernel<<<dim3((NN * 64) / 256), dim3(256), 0, stream>>>(x, W, b, left, right);
    att_kernel<<<dim3(NN / ROWS_PER_BLOCK), dim3(256), 0, stream>>>(adj, left, right, out);
}